// Round 4
// baseline (175.950 us; speedup 1.0000x reference)
//
#include <hip/hip_runtime.h>

#define EPS 1e-6f

__device__ __forceinline__ float elu1(float x) {
    // elu(x) + 1  ==  x > 0 ? x + 1 : exp(x)
    return x > 0.f ? x + 1.f : __expf(x);
}

// ---------------------------------------------------------------------------
// Phase 1: partial KV outer products. Grid (64 nh, 16 chunks), 256 threads =
// 4 INDEPENDENT waves (no barriers in the main loop). Each wave owns 64
// s-rows processed as 8 tiles of 8 rows, staged in a private 4 KB LDS slice.
// Lane tile: acc[8][8] at (m0=(l>>3)*8, d0=(l&7)*8).
// End: 2-round LDS combine of the 4 wave-partials (layout [w][l][33],
// conflict-free), then one coalesced dump: pkv[chunk][nh][kg][l],
// kg = i*8+j  (m = (l>>3)*8 + (kg>>3), d = (l&7)*8 + (kg&7)).
// __launch_bounds__(256,3): VGPR cap ~170 so the ~125-reg live set
// (acc 64 + prefetch 18 + ds temps) does NOT spill (round-3 bug: cap 96
// => scratch spills => 80 MB WRITE_SIZE and 91 us).
// ---------------------------------------------------------------------------
__global__ __launch_bounds__(256, 3) void kv_partial_kernel(
    const float* __restrict__ keys, const float* __restrict__ values,
    const float* __restrict__ mask, float* __restrict__ pkv,
    float* __restrict__ pks, int tiles)
{
    __shared__ float cmb[4 * 64 * 33];   // 33.8 KB combine buf; staging overlay
    __shared__ float ksr[4 * 64];        // per-wave ksum partials

    const int nh = blockIdx.x;
    const int n = nh >> 4, h = nh & 15;
    const int bc = blockIdx.y;           // chunk index (pkv slot)
    const int t = threadIdx.x;
    const int w = t >> 6, l = t & 63;

    // wave-private staging slices (overlaid on cmb; combine runs after sync)
    float* Ks = cmb + w * 1024;          // 8 rows x 64
    float* Vs = Ks + 512;

    const int m0 = (l >> 3) * 8, d0 = (l & 7) * 8;
    const int srow = l >> 4;             // staging row base (0..3)
    const int scol = (l & 15) * 4;       // staging col

    const int s0 = (bc * 4 + w) * (tiles * 8);
    const float* kb = keys   + ((size_t)(n * 4096 + s0) * 16 + h) * 64 + scol;
    const float* vb = values + ((size_t)(n * 4096 + s0) * 16 + h) * 64 + scol;
    const float* mb = mask + n * 4096 + s0;

    float4 kr[2], vr[2];
    float mr[2];
    float acc[8][8];
    #pragma unroll
    for (int i = 0; i < 8; ++i)
        #pragma unroll
        for (int j = 0; j < 8; ++j) acc[i][j] = 0.f;
    float4 ks4 = make_float4(0.f, 0.f, 0.f, 0.f);

    // prefetch tile 0 (4 float4 + 2 mask scalars per lane)
    #pragma unroll
    for (int k = 0; k < 2; ++k) {
        const int row = srow + 4 * k;
        kr[k] = *(const float4*)(kb + (size_t)row * 1024);
        vr[k] = *(const float4*)(vb + (size_t)row * 1024);
        mr[k] = mb[row];
    }

    for (int tile = 0; tile < tiles; ++tile) {
        // transform K (elu+mask), accumulate ksum partial, stage K and V
        #pragma unroll
        for (int k = 0; k < 2; ++k) {
            float4 kk = kr[k];
            const float msk = mr[k];
            kk.x = elu1(kk.x) * msk; kk.y = elu1(kk.y) * msk;
            kk.z = elu1(kk.z) * msk; kk.w = elu1(kk.w) * msk;
            ks4.x += kk.x; ks4.y += kk.y; ks4.z += kk.z; ks4.w += kk.w;
            ((float4*)Ks)[l + 64 * k] = kk;
            ((float4*)Vs)[l + 64 * k] = vr[k];
        }
        // issue next tile's global loads; they fly under the FMA loop
        if (tile + 1 < tiles) {
            const size_t off = (size_t)(tile + 1) * 8 * 1024;
            #pragma unroll
            for (int k = 0; k < 2; ++k) {
                const int row = srow + 4 * k;
                kr[k] = *(const float4*)(kb + off + (size_t)row * 1024);
                vr[k] = *(const float4*)(vb + off + (size_t)row * 1024);
                mr[k] = mb[(tile + 1) * 8 + row];
            }
        }
        // compute: per s, 4x ds_read_b128 -> 64 FMA
        #pragma unroll
        for (int s = 0; s < 8; ++s) {
            const float4 ka = *(const float4*)&Ks[s * 64 + d0];
            const float4 kc = *(const float4*)&Ks[s * 64 + d0 + 4];
            const float4 va = *(const float4*)&Vs[s * 64 + m0];
            const float4 vc = *(const float4*)&Vs[s * 64 + m0 + 4];
            const float kk[8] = {ka.x, ka.y, ka.z, ka.w, kc.x, kc.y, kc.z, kc.w};
            const float vv[8] = {va.x, va.y, va.z, va.w, vc.x, vc.y, vc.z, vc.w};
            #pragma unroll
            for (int i = 0; i < 8; ++i)
                #pragma unroll
                for (int j = 0; j < 8; ++j)
                    acc[i][j] = fmaf(vv[i], kk[j], acc[i][j]);
        }
    }

    // ksum partial: lane covers cols scol..scol+3; reduce over l>>4 groups
    ks4.x += __shfl_xor(ks4.x, 16, 64); ks4.y += __shfl_xor(ks4.y, 16, 64);
    ks4.z += __shfl_xor(ks4.z, 16, 64); ks4.w += __shfl_xor(ks4.w, 16, 64);
    ks4.x += __shfl_xor(ks4.x, 32, 64); ks4.y += __shfl_xor(ks4.y, 32, 64);
    ks4.z += __shfl_xor(ks4.z, 32, 64); ks4.w += __shfl_xor(ks4.w, 32, 64);
    if (l < 16) ((float4*)(ksr + w * 64))[l] = ks4;

    // 2-round cross-wave combine + coalesced dump
    float* pb = pkv + ((size_t)bc * 64 + nh) * 4096;
    #pragma unroll
    for (int r = 0; r < 2; ++r) {
        __syncthreads();   // staging/compute (or prior read) complete
        #pragma unroll
        for (int i2 = 0; i2 < 4; ++i2)
            #pragma unroll
            for (int j = 0; j < 8; ++j)
                cmb[w * 2112 + l * 33 + i2 * 8 + j] = acc[4 * r + i2][j];
        __syncthreads();
        #pragma unroll
        for (int r2 = 0; r2 < 8; ++r2) {
            const int f = r2 * 256 + t;
            const int k = f >> 6, lq = f & 63;
            float s = cmb[0 * 2112 + lq * 33 + k] + cmb[1 * 2112 + lq * 33 + k]
                    + cmb[2 * 2112 + lq * 33 + k] + cmb[3 * 2112 + lq * 33 + k];
            pb[r * 2048 + f] = s;
        }
        if (r == 0 && t < 64) {
            const float s = ksr[t] + ksr[64 + t] + ksr[128 + t] + ksr[192 + t];
            pks[((size_t)bc * 64 + nh) * 64 + t] = s;
        }
    }
}

// ---------------------------------------------------------------------------
// Reduce: kvt[nh][d][m] = sum_c pkv[c][nh][kg][l]
//         (m = (l>>3)*8 + (kg>>3), d = (l&7)*8 + (kg&7));
//         ksum[nh][d] = sum_c pks[c][nh][d].
// ---------------------------------------------------------------------------
__global__ __launch_bounds__(256) void kv_reduce_kernel(
    const float* __restrict__ pkv, const float* __restrict__ pks,
    float* __restrict__ kvt, float* __restrict__ ksum, int CH)
{
    const int nh = blockIdx.x;
    const int f4 = blockIdx.y * 256 + threadIdx.x;   // float4 slot 0..1023
    float4 s4 = make_float4(0.f, 0.f, 0.f, 0.f);
    for (int c = 0; c < CH; ++c) {
        const float4 v = *(const float4*)(pkv + ((size_t)c * 64 + nh) * 4096 + f4 * 4);
        s4.x += v.x; s4.y += v.y; s4.z += v.z; s4.w += v.w;
    }
    const float vals[4] = {s4.x, s4.y, s4.z, s4.w};
    const int k = f4 >> 4;
    const int lb = (f4 & 15) * 4;
    #pragma unroll
    for (int u = 0; u < 4; ++u) {
        const int l = lb + u;
        const int m = ((l >> 3) << 3) + (k >> 3);
        const int d = ((l & 7) << 3) + (k & 7);
        kvt[(size_t)nh * 4096 + d * 64 + m] = vals[u];
    }
    if (blockIdx.y == 0 && threadIdx.x < 64) {
        float s = 0.f;
        for (int c = 0; c < CH; ++c)
            s += pks[((size_t)c * 64 + nh) * 64 + threadIdx.x];
        ksum[nh * 64 + threadIdx.x] = s;
    }
}

// ---------------------------------------------------------------------------
// Phase 2: out[n,l,h,m] = z_l * sum_d Q'[l,d] * KVT[d,m],
//          z_l = 1/(sum_d Q'[l,d]*Ksum[d] + EPS)
// ---------------------------------------------------------------------------
__global__ __launch_bounds__(256) void out_kernel(
    const float* __restrict__ queries, const float* __restrict__ kvt,
    const float* __restrict__ ksum, float* __restrict__ out)
{
    __shared__ float QsT[64][132];  // [d][l]
    __shared__ float KVs[64][68];   // [d][m]
    __shared__ float Ksm[64];
    __shared__ float Zs[128];

    const int nh = blockIdx.x;
    const int n = nh >> 4, h = nh & 15;
    const int t = threadIdx.x;
    const int l0 = blockIdx.y * 128;

    #pragma unroll
    for (int k = 0; k < 4; ++k) {
        const int idx = t + k * 256;
        const int dd = idx >> 4, seg = idx & 15;
        const float4 v = *(const float4*)(kvt + (size_t)nh * 4096 + idx * 4);
        *(float4*)&KVs[dd][seg * 4] = v;
    }
    if (t < 64) Ksm[t] = ksum[nh * 64 + t];

    #pragma unroll
    for (int k = 0; k < 8; ++k) {
        const int idx = t + k * 256;
        const int row = idx >> 4, seg = idx & 15;
        const size_t g = ((size_t)(n * 4096 + l0 + row) * 16 + h) * 64 + seg * 4;
        float4 q4 = *(const float4*)(queries + g);
        q4.x = elu1(q4.x);
        q4.y = elu1(q4.y);
        q4.z = elu1(q4.z);
        q4.w = elu1(q4.w);
        QsT[seg * 4 + 0][row] = q4.x;
        QsT[seg * 4 + 1][row] = q4.y;
        QsT[seg * 4 + 2][row] = q4.z;
        QsT[seg * 4 + 3][row] = q4.w;
    }
    __syncthreads();

    if (t < 128) {
        float a = 0.f;
        #pragma unroll 8
        for (int d = 0; d < 64; ++d) a = fmaf(QsT[d][t], Ksm[d], a);
        Zs[t] = 1.f / (a + EPS);
    }
    __syncthreads();

    const int mg = t & 7, lg = t >> 3;
    const int m0 = mg * 8, lt = lg * 4;
    float acc[4][8];
    #pragma unroll
    for (int i = 0; i < 4; ++i)
        #pragma unroll
        for (int j = 0; j < 8; ++j) acc[i][j] = 0.f;

    #pragma unroll 4
    for (int d = 0; d < 64; ++d) {
        const float4 q4 = *(const float4*)&QsT[d][lt];
        const float4 a4 = *(const float4*)&KVs[d][m0];
        const float4 b4 = *(const float4*)&KVs[d][m0 + 4];
        const float qq[4] = {q4.x, q4.y, q4.z, q4.w};
        const float mm[8] = {a4.x, a4.y, a4.z, a4.w, b4.x, b4.y, b4.z, b4.w};
        #pragma unroll
        for (int i = 0; i < 4; ++i)
            #pragma unroll
            for (int j = 0; j < 8; ++j)
                acc[i][j] = fmaf(qq[i], mm[j], acc[i][j]);
    }

    #pragma unroll
    for (int i = 0; i < 4; ++i) {
        const float z = Zs[lt + i];
        const size_t g = ((size_t)(n * 4096 + l0 + lt + i) * 16 + h) * 64 + m0;
        float4 o;
        o.x = acc[i][0] * z; o.y = acc[i][1] * z;
        o.z = acc[i][2] * z; o.w = acc[i][3] * z;
        *(float4*)(out + g) = o;
        o.x = acc[i][4] * z; o.y = acc[i][5] * z;
        o.z = acc[i][6] * z; o.w = acc[i][7] * z;
        *(float4*)(out + g + 4) = o;
    }
}

extern "C" void kernel_launch(void* const* d_in, const int* in_sizes, int n_in,
                              void* d_out, int out_size, void* d_ws, size_t ws_size,
                              hipStream_t stream) {
    const float* queries = (const float*)d_in[0];
    const float* keys    = (const float*)d_in[1];
    const float* values  = (const float*)d_in[2];
    const float* mask    = (const float*)d_in[3];
    float* out = (float*)d_out;

    // chunk count = blocks per nh (4 waves each); adaptive to workspace size
    int CH = 16;
    while (CH > 2) {
        size_t need = ((size_t)CH * 64 * 4096 + (size_t)CH * 64 * 64 +
                       (size_t)64 * 4096 + 64 * 64) * sizeof(float);
        if (need <= ws_size) break;
        CH >>= 1;
    }
    const int tiles = 4096 / (CH * 4) / 8;   // 8-row tiles per wave

    float* pkv  = (float*)d_ws;                         // [CH][64][4096]
    float* pks  = pkv + (size_t)CH * 64 * 4096;         // [CH][64][64]
    float* kvt  = pks + (size_t)CH * 64 * 64;           // [64][64][64] (d,m)
    float* ksum = kvt + (size_t)64 * 4096;              // [64][64]

    kv_partial_kernel<<<dim3(64, CH), 256, 0, stream>>>(keys, values, mask,
                                                        pkv, pks, tiles);
    kv_reduce_kernel<<<dim3(64, 4), 256, 0, stream>>>(pkv, pks, kvt, ksum, CH);
    out_kernel<<<dim3(64, 32), 256, 0, stream>>>(queries, kvt, ksum, out);
}

// Round 5
// 100.798 us; speedup vs baseline: 1.7456x; 1.7456x over previous
//
#include <hip/hip_runtime.h>

#define EPS 1e-6f

typedef __attribute__((ext_vector_type(8))) short short8;   // 8 x bf16 bits
typedef __attribute__((ext_vector_type(16))) float f32x16;  // MFMA 32x32 acc

__device__ __forceinline__ float elu1(float x) {
    // elu(x) + 1  ==  x > 0 ? x + 1 : exp(x)
    return x > 0.f ? x + 1.f : __expf(x);
}

// fp32 -> bf16 bits, round-to-nearest-even
__device__ __forceinline__ short f2bf(float x) {
    unsigned u = __float_as_uint(x);
    return (short)((u + 0x7FFFu + ((u >> 16) & 1u)) >> 16);
}

// ---------------------------------------------------------------------------
// Phase 1: KV partials via MFMA. One WAVE per (nh, chunk); 64-thread blocks,
// no LDS, no barriers, acc in AGPRs (sidesteps the VALU-spill disease of
// rounds 2-4). Per 16 s-rows: 32 coalesced dword loads straight into
// mfma_f32_32x32x16_bf16 fragment layout (A = K'^T : row d=l&31+32*td,
// k=(l>>5)*8+j ; B = V : col m=l&31+32*tm, same k), elu+mask in fp32,
// pack to bf16, 4 MFMAs. Dump: pkv[chunk][nh][d][m] directly (C/D layout:
// col=l&31, row=(r&3)+8*(r>>2)+4*(l>>5)). ksum accumulated in fp32.
// ---------------------------------------------------------------------------
__global__ __launch_bounds__(64, 2) void kv_partial_kernel(
    const float* __restrict__ keys, const float* __restrict__ values,
    const float* __restrict__ mask, float* __restrict__ pkv,
    float* __restrict__ pks, int steps)
{
    const int nh = blockIdx.x;
    const int n = nh >> 4, h = nh & 15;
    const int chunk = blockIdx.y;
    const int l = threadIdx.x;
    const int half = l >> 5, col = l & 31;

    const int s0 = chunk * steps * 16;
    const size_t rowbase = ((size_t)(n * 4096 + s0 + 8 * half) * 16 + h) * 64 + col;
    const float* kb = keys + rowbase;
    const float* vb = values + rowbase;
    const float* mb = mask + n * 4096 + s0 + 8 * half;

    f32x16 acc[2][2];
    #pragma unroll
    for (int a = 0; a < 2; ++a)
        #pragma unroll
        for (int b = 0; b < 2; ++b)
            #pragma unroll
            for (int r = 0; r < 16; ++r) acc[a][b][r] = 0.f;

    float ks0 = 0.f, ks1 = 0.f;

    for (int st = 0; st < steps; ++st) {
        const float* kp = kb + (size_t)st * 16384;   // 16 rows * 1024 floats
        const float* vp = vb + (size_t)st * 16384;
        const float* mp = mb + st * 16;
        short8 ka0, ka1, va0, va1;
        #pragma unroll
        for (int j = 0; j < 8; ++j) {
            const float msk = mp[j];
            float k0 = kp[(size_t)j * 1024];
            float k1 = kp[(size_t)j * 1024 + 32];
            const float v0 = vp[(size_t)j * 1024];
            const float v1 = vp[(size_t)j * 1024 + 32];
            k0 = elu1(k0) * msk;
            k1 = elu1(k1) * msk;
            ks0 += k0; ks1 += k1;
            ka0[j] = f2bf(k0); ka1[j] = f2bf(k1);
            va0[j] = f2bf(v0); va1[j] = f2bf(v1);
        }
        acc[0][0] = __builtin_amdgcn_mfma_f32_32x32x16_bf16(ka0, va0, acc[0][0], 0, 0, 0);
        acc[0][1] = __builtin_amdgcn_mfma_f32_32x32x16_bf16(ka0, va1, acc[0][1], 0, 0, 0);
        acc[1][0] = __builtin_amdgcn_mfma_f32_32x32x16_bf16(ka1, va0, acc[1][0], 0, 0, 0);
        acc[1][1] = __builtin_amdgcn_mfma_f32_32x32x16_bf16(ka1, va1, acc[1][1], 0, 0, 0);
    }

    // ksum partial: ks0 covers d=col (j-rows of this half), ks1 covers d=col+32
    ks0 += __shfl_xor(ks0, 32);
    ks1 += __shfl_xor(ks1, 32);
    pks[((size_t)chunk * 64 + nh) * 64 + l] = half ? ks1 : ks0;

    // dump partial, already in [d][m] order; each store = 2x128B segments
    float* pb = pkv + ((size_t)chunk * 64 + nh) * 4096;
    #pragma unroll
    for (int td = 0; td < 2; ++td)
        #pragma unroll
        for (int tm = 0; tm < 2; ++tm)
            #pragma unroll
            for (int r = 0; r < 16; ++r) {
                const int d = 32 * td + (r & 3) + 8 * (r >> 2) + 4 * half;
                pb[(size_t)d * 64 + 32 * tm + col] = acc[td][tm][r];
            }
}

// ---------------------------------------------------------------------------
// Reduce: kvt[nh][d][m] = sum_c pkv[c][nh][d][m];  ksum[nh][d] = sum_c pks.
// Pure float4 streaming sum (pkv is already in final [d][m] order).
// ---------------------------------------------------------------------------
__global__ __launch_bounds__(256) void kv_reduce_kernel(
    const float* __restrict__ pkv, const float* __restrict__ pks,
    float* __restrict__ kvt, float* __restrict__ ksum, int CH)
{
    const int nh = blockIdx.x;
    const int f4 = blockIdx.y * 256 + threadIdx.x;   // float4 slot 0..1023
    float4 s4 = make_float4(0.f, 0.f, 0.f, 0.f);
    for (int c = 0; c < CH; ++c) {
        const float4 v = *(const float4*)(pkv + ((size_t)c * 64 + nh) * 4096 + f4 * 4);
        s4.x += v.x; s4.y += v.y; s4.z += v.z; s4.w += v.w;
    }
    *(float4*)(kvt + (size_t)nh * 4096 + f4 * 4) = s4;

    if (blockIdx.y == 0 && threadIdx.x < 64) {
        float s = 0.f;
        for (int c = 0; c < CH; ++c)
            s += pks[((size_t)c * 64 + nh) * 64 + threadIdx.x];
        ksum[nh * 64 + threadIdx.x] = s;
    }
}

// ---------------------------------------------------------------------------
// Phase 2: out[n,l,h,m] = z_l * sum_d Q'[l,d] * KVT[d,m],
//          z_l = 1/(sum_d Q'[l,d]*Ksum[d] + EPS)
// ---------------------------------------------------------------------------
__global__ __launch_bounds__(256) void out_kernel(
    const float* __restrict__ queries, const float* __restrict__ kvt,
    const float* __restrict__ ksum, float* __restrict__ out)
{
    __shared__ float QsT[64][132];  // [d][l]
    __shared__ float KVs[64][68];   // [d][m]
    __shared__ float Ksm[64];
    __shared__ float Zs[128];

    const int nh = blockIdx.x;
    const int n = nh >> 4, h = nh & 15;
    const int t = threadIdx.x;
    const int l0 = blockIdx.y * 128;

    #pragma unroll
    for (int k = 0; k < 4; ++k) {
        const int idx = t + k * 256;
        const int dd = idx >> 4, seg = idx & 15;
        const float4 v = *(const float4*)(kvt + (size_t)nh * 4096 + idx * 4);
        *(float4*)&KVs[dd][seg * 4] = v;
    }
    if (t < 64) Ksm[t] = ksum[nh * 64 + t];

    #pragma unroll
    for (int k = 0; k < 8; ++k) {
        const int idx = t + k * 256;
        const int row = idx >> 4, seg = idx & 15;
        const size_t g = ((size_t)(n * 4096 + l0 + row) * 16 + h) * 64 + seg * 4;
        float4 q4 = *(const float4*)(queries + g);
        q4.x = elu1(q4.x);
        q4.y = elu1(q4.y);
        q4.z = elu1(q4.z);
        q4.w = elu1(q4.w);
        QsT[seg * 4 + 0][row] = q4.x;
        QsT[seg * 4 + 1][row] = q4.y;
        QsT[seg * 4 + 2][row] = q4.z;
        QsT[seg * 4 + 3][row] = q4.w;
    }
    __syncthreads();

    if (t < 128) {
        float a = 0.f;
        #pragma unroll 8
        for (int d = 0; d < 64; ++d) a = fmaf(QsT[d][t], Ksm[d], a);
        Zs[t] = 1.f / (a + EPS);
    }
    __syncthreads();

    const int mg = t & 7, lg = t >> 3;
    const int m0 = mg * 8, lt = lg * 4;
    float acc[4][8];
    #pragma unroll
    for (int i = 0; i < 4; ++i)
        #pragma unroll
        for (int j = 0; j < 8; ++j) acc[i][j] = 0.f;

    #pragma unroll 4
    for (int d = 0; d < 64; ++d) {
        const float4 q4 = *(const float4*)&QsT[d][lt];
        const float4 a4 = *(const float4*)&KVs[d][m0];
        const float4 b4 = *(const float4*)&KVs[d][m0 + 4];
        const float qq[4] = {q4.x, q4.y, q4.z, q4.w};
        const float mm[8] = {a4.x, a4.y, a4.z, a4.w, b4.x, b4.y, b4.z, b4.w};
        #pragma unroll
        for (int i = 0; i < 4; ++i)
            #pragma unroll
            for (int j = 0; j < 8; ++j)
                acc[i][j] = fmaf(qq[i], mm[j], acc[i][j]);
    }

    #pragma unroll
    for (int i = 0; i < 4; ++i) {
        const float z = Zs[lt + i];
        const size_t g = ((size_t)(n * 4096 + l0 + lt + i) * 16 + h) * 64 + m0;
        float4 o;
        o.x = acc[i][0] * z; o.y = acc[i][1] * z;
        o.z = acc[i][2] * z; o.w = acc[i][3] * z;
        *(float4*)(out + g) = o;
        o.x = acc[i][4] * z; o.y = acc[i][5] * z;
        o.z = acc[i][6] * z; o.w = acc[i][7] * z;
        *(float4*)(out + g + 4) = o;
    }
}

extern "C" void kernel_launch(void* const* d_in, const int* in_sizes, int n_in,
                              void* d_out, int out_size, void* d_ws, size_t ws_size,
                              hipStream_t stream) {
    const float* queries = (const float*)d_in[0];
    const float* keys    = (const float*)d_in[1];
    const float* values  = (const float*)d_in[2];
    const float* mask    = (const float*)d_in[3];
    float* out = (float*)d_out;

    // one wave per (nh, chunk); adaptive chunk count vs workspace size
    int CH = 32;
    while (CH > 2) {
        size_t need = ((size_t)CH * 64 * 4096 + (size_t)CH * 64 * 64 +
                       (size_t)64 * 4096 + 64 * 64) * sizeof(float);
        if (need <= ws_size) break;
        CH >>= 1;
    }
    const int steps = 4096 / (CH * 16);   // 16-row K-steps per wave

    float* pkv  = (float*)d_ws;                         // [CH][64][64][64] (d,m)
    float* pks  = pkv + (size_t)CH * 64 * 4096;         // [CH][64][64]
    float* kvt  = pks + (size_t)CH * 64 * 64;           // [64][64][64] (d,m)
    float* ksum = kvt + (size_t)64 * 4096;              // [64][64]

    kv_partial_kernel<<<dim3(64, CH), 64, 0, stream>>>(keys, values, mask,
                                                       pkv, pks, steps);
    kv_reduce_kernel<<<dim3(64, 4), 256, 0, stream>>>(pkv, pks, kvt, ksum, CH);
    out_kernel<<<dim3(64, 32), 256, 0, stream>>>(queries, kvt, ksum, out);
}

// Round 6
// 97.852 us; speedup vs baseline: 1.7981x; 1.0301x over previous
//
#include <hip/hip_runtime.h>

#define EPS 1e-6f

typedef __attribute__((ext_vector_type(8))) short short8;   // 8 x bf16 bits
typedef __attribute__((ext_vector_type(16))) float f32x16;  // MFMA 32x32 acc

__device__ __forceinline__ float elu1(float x) {
    // elu(x) + 1  ==  x > 0 ? x + 1 : exp(x)
    return x > 0.f ? x + 1.f : __expf(x);
}

// fp32 -> bf16 bits, round-to-nearest-even
__device__ __forceinline__ short f2bf(float x) {
    unsigned u = __float_as_uint(x);
    return (short)((u + 0x7FFFu + ((u >> 16) & 1u)) >> 16);
}

// ---------------------------------------------------------------------------
// Phase 1: KV partials via MFMA. One WAVE per (nh, chunk); no LDS, no
// barriers, acc in AGPRs. Round-6 change: EXPLICIT register double-buffer —
// step st+1's 40 loads are issued before step st's convert+MFMA (unroll-by-2,
// two named buffer sets, all compile-time indices), so the ~600-cy memory
// round trip hides under compute instead of serializing (round 5: 66 us
// latency-bound, identical dur whether HBM- or L3-served).
// Fragment mapping (verified passing in R5):
//   A (K'^T): lane holds row d=l&31 (+32*td), k=(l>>5)*8+j
//   B (V):    lane holds col m=l&31 (+32*tm), same k
//   C/D:      col=l&31, row=(r&3)+8*(r>>2)+4*(l>>5)
// Dump: pkv[chunk][nh][d][m] directly; ksum partials in fp32.
// ---------------------------------------------------------------------------
__global__ __launch_bounds__(64, 2) void kv_partial_kernel(
    const float* __restrict__ keys, const float* __restrict__ values,
    const float* __restrict__ mask, float* __restrict__ pkv,
    float* __restrict__ pks, int steps)
{
    const int nh = blockIdx.x;
    const int n = nh >> 4, h = nh & 15;
    const int chunk = blockIdx.y;
    const int l = threadIdx.x;
    const int half = l >> 5, col = l & 31;

    const int s0 = chunk * steps * 16;
    const size_t rowbase = ((size_t)(n * 4096 + s0 + 8 * half) * 16 + h) * 64 + col;
    const float* kb = keys + rowbase;
    const float* vb = values + rowbase;
    const float* mb = mask + n * 4096 + s0 + 8 * half;

    f32x16 acc[2][2];
    #pragma unroll
    for (int a = 0; a < 2; ++a)
        #pragma unroll
        for (int b = 0; b < 2; ++b)
            #pragma unroll
            for (int r = 0; r < 16; ++r) acc[a][b][r] = 0.f;

    float ks0 = 0.f, ks1 = 0.f;

    float kA[16], vA[16], mA[8];
    float kB[16], vB[16], mB[8];

#define LOADSTEP(st, kd, vd, md)                                         \
    {                                                                    \
        const float* kp = kb + (size_t)(st) * 16384;                     \
        const float* vp = vb + (size_t)(st) * 16384;                     \
        const float* mp = mb + (st) * 16;                                \
        _Pragma("unroll")                                                \
        for (int j = 0; j < 8; ++j) {                                    \
            kd[2 * j]     = kp[(size_t)j * 1024];                        \
            kd[2 * j + 1] = kp[(size_t)j * 1024 + 32];                   \
            vd[2 * j]     = vp[(size_t)j * 1024];                        \
            vd[2 * j + 1] = vp[(size_t)j * 1024 + 32];                   \
            md[j]         = mp[j];                                       \
        }                                                                \
    }

#define COMPUTESTEP(kd, vd, md)                                          \
    {                                                                    \
        short8 ka0, ka1, va0, va1;                                       \
        _Pragma("unroll")                                                \
        for (int j = 0; j < 8; ++j) {                                    \
            const float msk = md[j];                                     \
            const float k0 = elu1(kd[2 * j]) * msk;                      \
            const float k1 = elu1(kd[2 * j + 1]) * msk;                  \
            ks0 += k0; ks1 += k1;                                        \
            ka0[j] = f2bf(k0); ka1[j] = f2bf(k1);                        \
            va0[j] = f2bf(vd[2 * j]); va1[j] = f2bf(vd[2 * j + 1]);      \
        }                                                                \
        acc[0][0] = __builtin_amdgcn_mfma_f32_32x32x16_bf16(ka0, va0, acc[0][0], 0, 0, 0); \
        acc[0][1] = __builtin_amdgcn_mfma_f32_32x32x16_bf16(ka0, va1, acc[0][1], 0, 0, 0); \
        acc[1][0] = __builtin_amdgcn_mfma_f32_32x32x16_bf16(ka1, va0, acc[1][0], 0, 0, 0); \
        acc[1][1] = __builtin_amdgcn_mfma_f32_32x32x16_bf16(ka1, va1, acc[1][1], 0, 0, 0); \
    }

    LOADSTEP(0, kA, vA, mA);
    for (int st = 0; st < steps; st += 2) {       // steps is even (>=8)
        if (st + 1 < steps) LOADSTEP(st + 1, kB, vB, mB);
        COMPUTESTEP(kA, vA, mA);
        if (st + 2 < steps) LOADSTEP(st + 2, kA, vA, mA);
        if (st + 1 < steps) COMPUTESTEP(kB, vB, mB);
    }
#undef LOADSTEP
#undef COMPUTESTEP

    // ksum partial: ks0 covers d=col (this half's rows), ks1 covers d=col+32
    ks0 += __shfl_xor(ks0, 32);
    ks1 += __shfl_xor(ks1, 32);
    pks[((size_t)chunk * 64 + nh) * 64 + l] = half ? ks1 : ks0;

    // dump partial, already in [d][m] order; each store = 2x128B segments
    float* pb = pkv + ((size_t)chunk * 64 + nh) * 4096;
    #pragma unroll
    for (int td = 0; td < 2; ++td)
        #pragma unroll
        for (int tm = 0; tm < 2; ++tm)
            #pragma unroll
            for (int r = 0; r < 16; ++r) {
                const int d = 32 * td + (r & 3) + 8 * (r >> 2) + 4 * half;
                pb[(size_t)d * 64 + 32 * tm + col] = acc[td][tm][r];
            }
}

// ---------------------------------------------------------------------------
// Reduce: kvt[nh][d][m] = sum_c pkv[c][nh][d][m];  ksum[nh][d] = sum_c pks.
// ---------------------------------------------------------------------------
__global__ __launch_bounds__(256) void kv_reduce_kernel(
    const float* __restrict__ pkv, const float* __restrict__ pks,
    float* __restrict__ kvt, float* __restrict__ ksum, int CH)
{
    const int nh = blockIdx.x;
    const int f4 = blockIdx.y * 256 + threadIdx.x;   // float4 slot 0..1023
    float4 s4 = make_float4(0.f, 0.f, 0.f, 0.f);
    for (int c = 0; c < CH; ++c) {
        const float4 v = *(const float4*)(pkv + ((size_t)c * 64 + nh) * 4096 + f4 * 4);
        s4.x += v.x; s4.y += v.y; s4.z += v.z; s4.w += v.w;
    }
    *(float4*)(kvt + (size_t)nh * 4096 + f4 * 4) = s4;

    if (blockIdx.y == 0 && threadIdx.x < 64) {
        float s = 0.f;
        for (int c = 0; c < CH; ++c)
            s += pks[((size_t)c * 64 + nh) * 64 + threadIdx.x];
        ksum[nh * 64 + threadIdx.x] = s;
    }
}

// ---------------------------------------------------------------------------
// Phase 2: out[n,l,h,m] = z_l * sum_d Q'[l,d] * KVT[d,m],
//          z_l = 1/(sum_d Q'[l,d]*Ksum[d] + EPS)
// ---------------------------------------------------------------------------
__global__ __launch_bounds__(256) void out_kernel(
    const float* __restrict__ queries, const float* __restrict__ kvt,
    const float* __restrict__ ksum, float* __restrict__ out)
{
    __shared__ float QsT[64][132];  // [d][l]
    __shared__ float KVs[64][68];   // [d][m]
    __shared__ float Ksm[64];
    __shared__ float Zs[128];

    const int nh = blockIdx.x;
    const int n = nh >> 4, h = nh & 15;
    const int t = threadIdx.x;
    const int l0 = blockIdx.y * 128;

    #pragma unroll
    for (int k = 0; k < 4; ++k) {
        const int idx = t + k * 256;
        const int dd = idx >> 4, seg = idx & 15;
        const float4 v = *(const float4*)(kvt + (size_t)nh * 4096 + idx * 4);
        *(float4*)&KVs[dd][seg * 4] = v;
    }
    if (t < 64) Ksm[t] = ksum[nh * 64 + t];

    #pragma unroll
    for (int k = 0; k < 8; ++k) {
        const int idx = t + k * 256;
        const int row = idx >> 4, seg = idx & 15;
        const size_t g = ((size_t)(n * 4096 + l0 + row) * 16 + h) * 64 + seg * 4;
        float4 q4 = *(const float4*)(queries + g);
        q4.x = elu1(q4.x);
        q4.y = elu1(q4.y);
        q4.z = elu1(q4.z);
        q4.w = elu1(q4.w);
        QsT[seg * 4 + 0][row] = q4.x;
        QsT[seg * 4 + 1][row] = q4.y;
        QsT[seg * 4 + 2][row] = q4.z;
        QsT[seg * 4 + 3][row] = q4.w;
    }
    __syncthreads();

    if (t < 128) {
        float a = 0.f;
        #pragma unroll 8
        for (int d = 0; d < 64; ++d) a = fmaf(QsT[d][t], Ksm[d], a);
        Zs[t] = 1.f / (a + EPS);
    }
    __syncthreads();

    const int mg = t & 7, lg = t >> 3;
    const int m0 = mg * 8, lt = lg * 4;
    float acc[4][8];
    #pragma unroll
    for (int i = 0; i < 4; ++i)
        #pragma unroll
        for (int j = 0; j < 8; ++j) acc[i][j] = 0.f;

    #pragma unroll 4
    for (int d = 0; d < 64; ++d) {
        const float4 q4 = *(const float4*)&QsT[d][lt];
        const float4 a4 = *(const float4*)&KVs[d][m0];
        const float4 b4 = *(const float4*)&KVs[d][m0 + 4];
        const float qq[4] = {q4.x, q4.y, q4.z, q4.w};
        const float mm[8] = {a4.x, a4.y, a4.z, a4.w, b4.x, b4.y, b4.z, b4.w};
        #pragma unroll
        for (int i = 0; i < 4; ++i)
            #pragma unroll
            for (int j = 0; j < 8; ++j)
                acc[i][j] = fmaf(qq[i], mm[j], acc[i][j]);
    }

    #pragma unroll
    for (int i = 0; i < 4; ++i) {
        const float z = Zs[lt + i];
        const size_t g = ((size_t)(n * 4096 + l0 + lt + i) * 16 + h) * 64 + m0;
        float4 o;
        o.x = acc[i][0] * z; o.y = acc[i][1] * z;
        o.z = acc[i][2] * z; o.w = acc[i][3] * z;
        *(float4*)(out + g) = o;
        o.x = acc[i][4] * z; o.y = acc[i][5] * z;
        o.z = acc[i][6] * z; o.w = acc[i][7] * z;
        *(float4*)(out + g + 4) = o;
    }
}

extern "C" void kernel_launch(void* const* d_in, const int* in_sizes, int n_in,
                              void* d_out, int out_size, void* d_ws, size_t ws_size,
                              hipStream_t stream) {
    const float* queries = (const float*)d_in[0];
    const float* keys    = (const float*)d_in[1];
    const float* values  = (const float*)d_in[2];
    const float* mask    = (const float*)d_in[3];
    float* out = (float*)d_out;

    // one wave per (nh, chunk); adaptive chunk count vs workspace size
    int CH = 32;
    while (CH > 2) {
        size_t need = ((size_t)CH * 64 * 4096 + (size_t)CH * 64 * 64 +
                       (size_t)64 * 4096 + 64 * 64) * sizeof(float);
        if (need <= ws_size) break;
        CH >>= 1;
    }
    const int steps = 4096 / (CH * 16);   // 16-row K-steps per wave (even)

    float* pkv  = (float*)d_ws;                         // [CH][64][64][64] (d,m)
    float* pks  = pkv + (size_t)CH * 64 * 4096;         // [CH][64][64]
    float* kvt  = pks + (size_t)CH * 64 * 64;           // [64][64][64] (d,m)
    float* ksum = kvt + (size_t)64 * 4096;              // [64][64]

    kv_partial_kernel<<<dim3(64, CH), 64, 0, stream>>>(keys, values, mask,
                                                       pkv, pks, steps);
    kv_reduce_kernel<<<dim3(64, 4), 256, 0, stream>>>(pkv, pks, kvt, ksum, CH);
    out_kernel<<<dim3(64, 32), 256, 0, stream>>>(queries, kvt, ksum, out);
}